// Round 9
// baseline (359.211 us; speedup 1.0000x reference)
//
#include <hip/hip_runtime.h>
#include <hip/hip_bf16.h>

#define L_SEQ 1024
#define CCH   512
#define NB    8

typedef __bf16 bf16_t;
typedef __bf16 bf16x4 __attribute__((ext_vector_type(4)));
typedef __bf16 bf16x8 __attribute__((ext_vector_type(8)));
typedef float  f32x4  __attribute__((ext_vector_type(4)));

__device__ __forceinline__ void gload_lds16(const void* g, void* l) {
  __builtin_amdgcn_global_load_lds((const __attribute__((address_space(1))) void*)g,
                                   (__attribute__((address_space(3))) void*)l, 16, 0, 0);
}

// ---------------- all weight conversions + PE table in one kernel ----------------
__global__ __launch_bounds__(256) void cvtall_kernel(
    const float* __restrict__ pw_w, const float* __restrict__ Wq,
    const float* __restrict__ Wk, const float* __restrict__ Wv,
    const float* __restrict__ Wo, const float* __restrict__ Wf,
    const float* __restrict__ dw_w,
    bf16_t* __restrict__ WPW, bf16_t* __restrict__ WQKV,
    bf16_t* __restrict__ WOB, bf16_t* __restrict__ WFB,
    float* __restrict__ WT, float* __restrict__ PET) {
  int idx = blockIdx.x * 256 + threadIdx.x;
  if (idx < 1048576) { WPW[idx] = (bf16_t)pw_w[idx]; return; }
  idx -= 1048576;
  if (idx < 262144) { WQKV[idx] = (bf16_t)Wq[idx]; return; }
  idx -= 262144;
  if (idx < 262144) { WQKV[262144 + idx] = (bf16_t)Wk[idx]; return; }
  idx -= 262144;
  if (idx < 262144) { WQKV[524288 + idx] = (bf16_t)Wv[idx]; return; }
  idx -= 262144;
  if (idx < 262144) { WOB[idx] = (bf16_t)Wo[idx]; return; }
  idx -= 262144;
  if (idx < 262144) { WFB[idx] = (bf16_t)Wf[idx]; return; }
  idx -= 262144;
  if (idx < 14336) {  // dw weights transpose [i][c][t] -> [i][t][c], fp32
    int i = idx / 3584, r = idx % 3584, t = r >> 9, c = r & 511;
    WT[idx] = dw_w[i * 3584 + c * 7 + t];
    return;
  }
  idx -= 14336;
  if (idx < 524288) {  // PE table
    int l = idx >> 9, c = idx & 511;
    float div = expf(-(float)(2 * (c >> 1)) * (9.210340371976184f / 512.0f));
    float ang = (float)l * div;
    PET[idx] = (c & 1) ? cosf(ang) : sinf(ang);
  }
}

// ---------------- x + PE, transpose (B,C,L)->(B,L,C) ----------------
__global__ __launch_bounds__(256) void pe_kernel(const float* __restrict__ x,
                                                 const float* __restrict__ PET,
                                                 float* __restrict__ out) {
  __shared__ float tile[32][33];
  int l0 = blockIdx.x * 32, c0 = blockIdx.y * 32, b = blockIdx.z;
  int tx = threadIdx.x, ty = threadIdx.y;
#pragma unroll
  for (int r = 0; r < 32; r += 8)
    tile[ty + r][tx] = x[(size_t)(b * CCH + c0 + ty + r) * L_SEQ + l0 + tx];
  __syncthreads();
#pragma unroll
  for (int r = 0; r < 32; r += 8) {
    int l = l0 + ty + r, c = c0 + tx;
    out[(size_t)(b * L_SEQ + l) * CCH + c] = tile[tx][ty + r] + PET[l * CCH + c];
  }
}

// ---------------- standalone LN stats (used once, after pe) ----------------
__global__ __launch_bounds__(256) void stats_kernel(const float* __restrict__ in,
                                                    float* __restrict__ Psum,
                                                    float* __restrict__ Psq) {
  int w = threadIdx.x >> 6, l = threadIdx.x & 63;
  int row = blockIdx.x * 4 + w;
  const float* p = in + (size_t)row * CCH + l * 8;
  float v[8];
  *(float4*)(&v[0]) = *(const float4*)p;
  *(float4*)(&v[4]) = *(const float4*)(p + 4);
  float s = 0.f, q = 0.f;
#pragma unroll
  for (int j = 0; j < 8; j++) { s += v[j]; q += v[j] * v[j]; }
  s += __shfl_xor(s, 1); q += __shfl_xor(q, 1);
  s += __shfl_xor(s, 2); q += __shfl_xor(q, 2);
  s += __shfl_xor(s, 4); q += __shfl_xor(q, 4);
  if ((l & 7) == 0) {
    Psum[row * 8 + (l >> 3)] = s;
    Psq[row * 8 + (l >> 3)] = q;
  }
}

// ---------------- LN apply (stats from partials) -> bf16 ----------------
__global__ __launch_bounds__(256) void ln_apply_kernel(const float* __restrict__ in,
                                                       const float* __restrict__ Psum,
                                                       const float* __restrict__ Psq,
                                                       const float* __restrict__ gam,
                                                       const float* __restrict__ bet,
                                                       bf16_t* __restrict__ out) {
  int w = threadIdx.x >> 6, l = threadIdx.x & 63;
  int row = blockIdx.x * 4 + w;
  float v0 = 0.f;
  if (l < 8) v0 = Psum[row * 8 + l];
  else if (l < 16) v0 = Psq[row * 8 + (l - 8)];
  v0 += __shfl_xor(v0, 1); v0 += __shfl_xor(v0, 2); v0 += __shfl_xor(v0, 4);
  float sum = __shfl(v0, 0), sq = __shfl(v0, 8);
  float mean = sum * (1.0f / 512.0f);
  float var = sq * (1.0f / 512.0f) - mean * mean;
  float inv = rsqrtf(var + 1e-5f);
  const float* p = in + (size_t)row * CCH + l * 8;
  float v[8], gv[8], bv[8];
  *(float4*)(&v[0]) = *(const float4*)p;
  *(float4*)(&v[4]) = *(const float4*)(p + 4);
  *(float4*)(&gv[0]) = *(const float4*)(gam + l * 8);
  *(float4*)(&gv[4]) = *(const float4*)(gam + l * 8 + 4);
  *(float4*)(&bv[0]) = *(const float4*)(bet + l * 8);
  *(float4*)(&bv[4]) = *(const float4*)(bet + l * 8 + 4);
  bf16x8 o;
#pragma unroll
  for (int j = 0; j < 8; j++) o[j] = (bf16_t)((v[j] - mean) * inv * gv[j] + bv[j]);
  *(bf16x8*)(out + (size_t)row * CCH + l * 8) = o;
}

// ---------------- fused LN + depthwise conv K=7 ----------------
__global__ __launch_bounds__(256) void dwln_kernel(const float* __restrict__ in,
                                                   const float* __restrict__ Psum,
                                                   const float* __restrict__ Psq,
                                                   const float* __restrict__ gam,
                                                   const float* __restrict__ bet,
                                                   const float* __restrict__ wtt,  // [7][512]
                                                   const float* __restrict__ dbias,
                                                   bf16_t* __restrict__ out) {
  int idx = blockIdx.x * 256 + threadIdx.x;
  int lane = threadIdx.x & 63;  // == channel group cg
  int row = idx >> 6;
  int l = row & (L_SEQ - 1);
  float m_ = 0.f, i_ = 0.f;
  if (lane < 7) {
    int ll = l + lane - 3;
    if (ll >= 0 && ll < L_SEQ) {
      int rr = row + lane - 3;
      float s = 0.f, q = 0.f;
#pragma unroll
      for (int c = 0; c < 8; c++) { s += Psum[rr * 8 + c]; q += Psq[rr * 8 + c]; }
      float mm = s * (1.0f / 512.0f);
      m_ = mm;
      i_ = rsqrtf(q * (1.0f / 512.0f) - mm * mm + 1e-5f);
    }
  }
  float gv[8], bv[8], acc[8];
  *(float4*)&gv[0] = *(const float4*)(gam + lane * 8);
  *(float4*)&gv[4] = *(const float4*)(gam + lane * 8 + 4);
  *(float4*)&bv[0] = *(const float4*)(bet + lane * 8);
  *(float4*)&bv[4] = *(const float4*)(bet + lane * 8 + 4);
  *(float4*)&acc[0] = *(const float4*)(dbias + lane * 8);
  *(float4*)&acc[4] = *(const float4*)(dbias + lane * 8 + 4);
#pragma unroll
  for (int t = 0; t < 7; t++) {
    float mt = __shfl(m_, t), it = __shfl(i_, t);
    int ll = l + t - 3;
    if (ll >= 0 && ll < L_SEQ) {
      const float* p = in + (size_t)(row + t - 3) * CCH + lane * 8;
      float v[8], wv[8];
      *(float4*)&v[0] = *(const float4*)p;
      *(float4*)&v[4] = *(const float4*)(p + 4);
      *(float4*)&wv[0] = *(const float4*)(wtt + t * CCH + lane * 8);
      *(float4*)&wv[4] = *(const float4*)(wtt + t * CCH + lane * 8 + 4);
#pragma unroll
      for (int j = 0; j < 8; j++)
        acc[j] += ((v[j] - mt) * it * gv[j] + bv[j]) * wv[j];
    }
  }
  bf16x8 o;
#pragma unroll
  for (int j = 0; j < 8; j++) o[j] = (bf16_t)acc[j];
  *(bf16x8*)&out[(size_t)row * CCH + lane * 8] = o;
}

// ======== GEMM core: BM=32 BN=256 BK=64, double-buffered 2-phase ========
// 4 waves: wave w owns 32x64 output at col w*64. A re-fetched only N/256 times.
#define GEMM_STAGE(SRCA, SRCB, BI, K0)                                            \
  do {                                                                            \
    {                                                                             \
      int row_ = w * 8 + srow;                                                    \
      int off_ = (scb ^ ((row_ & 7) << 4)) >> 1;                                  \
      gload_lds16(SRCA + (size_t)(m0 + row_) * CCH + (K0) + off_,                 \
                  &As[BI][(w * 8) * 64]);                                         \
    }                                                                             \
    _Pragma("unroll") for (int cc = 0; cc < 8; cc++) {                            \
      int row_ = cc * 32 + w * 8 + srow;                                          \
      int off_ = (scb ^ ((row_ & 7) << 4)) >> 1;                                  \
      gload_lds16(SRCB + (size_t)(n0 + row_) * CCH + (K0) + off_,                 \
                  &Bs[BI][(cc * 32 + w * 8) * 64]);                               \
    }                                                                             \
  } while (0)

#define GEMM_COMPUTE(BI)                                                          \
  do {                                                                            \
    _Pragma("unroll") for (int ks = 0; ks < 2; ks++) {                            \
      bf16x8 fa[2], fb[4];                                                        \
      _Pragma("unroll") for (int i = 0; i < 2; i++) {                             \
        int ra = i * 16 + lc;                                                     \
        fa[i] = *(const bf16x8*)&As[BI][ra * 64 +                                 \
                 (((ks * 64 + lg * 16) ^ ((ra & 7) << 4)) >> 1)];                 \
      }                                                                           \
      _Pragma("unroll") for (int j = 0; j < 4; j++) {                             \
        int rb = w * 64 + j * 16 + lc;                                            \
        fb[j] = *(const bf16x8*)&Bs[BI][rb * 64 +                                 \
                 (((ks * 64 + lg * 16) ^ ((rb & 7) << 4)) >> 1)];                 \
      }                                                                           \
      _Pragma("unroll") for (int i = 0; i < 2; i++)                               \
        _Pragma("unroll") for (int j = 0; j < 4; j++)                             \
          acc[i][j] = __builtin_amdgcn_mfma_f32_16x16x32_bf16(fa[i], fb[j],       \
                                                              acc[i][j], 0, 0, 0);\
    }                                                                             \
  } while (0)

// out[m,n] = A[m,:] . W[n,:] (+bias, relu, res); optional LN partial stats.
// grid (M/32, N/256)
template <int RELU, int RES, int BF16OUT, int STATS>
__global__ __launch_bounds__(256) void gemm_kernel(const bf16_t* __restrict__ A,
                                                   const bf16_t* __restrict__ W,
                                                   const float* __restrict__ bias,
                                                   const float* __restrict__ res,
                                                   float* __restrict__ outf,
                                                   bf16_t* __restrict__ outb,
                                                   float* __restrict__ Psum,
                                                   float* __restrict__ Psq) {
  __shared__ __align__(16) bf16_t As[2][32 * 64];
  __shared__ __align__(16) bf16_t Bs[2][256 * 64];
  int tid = threadIdx.x;
  int w = tid >> 6, l = tid & 63;
  int m0 = blockIdx.x * 32, n0 = blockIdx.y * 256;
  int lc = l & 15, lg = l >> 4;
  int srow = l >> 3, scb = (l & 7) * 16;
  f32x4 acc[2][4];
#pragma unroll
  for (int i = 0; i < 2; i++)
#pragma unroll
    for (int j = 0; j < 4; j++) acc[i][j] = f32x4{0.f, 0.f, 0.f, 0.f};

  GEMM_STAGE(A, W, 0, 0);
  __syncthreads();
  int cur = 0;
  for (int t = 0; t < 8; t++) {
    if (t < 7) GEMM_STAGE(A, W, cur ^ 1, (t + 1) * 64);
    GEMM_COMPUTE(cur);
    __syncthreads();
    cur ^= 1;
  }

  float ps[2][4], pq[2][4];
  if (STATS) {
#pragma unroll
    for (int i = 0; i < 2; i++)
#pragma unroll
      for (int r = 0; r < 4; r++) { ps[i][r] = 0.f; pq[i][r] = 0.f; }
  }
#pragma unroll
  for (int i = 0; i < 2; i++) {
    int mbase = m0 + i * 16 + lg * 4;
#pragma unroll
    for (int j = 0; j < 4; j++) {
      int n = n0 + w * 64 + j * 16 + lc;
      float bn = bias[n];
#pragma unroll
      for (int r = 0; r < 4; r++) {
        int m = mbase + r;
        float v2 = acc[i][j][r] + bn;
        if (RELU) v2 = fmaxf(v2, 0.f);
        if (RES) v2 += res[(size_t)m * CCH + n];
        if (BF16OUT) outb[(size_t)m * CCH + n] = (bf16_t)v2;
        else outf[(size_t)m * CCH + n] = v2;
        if (STATS) { ps[i][r] += v2; pq[i][r] += v2 * v2; }
      }
    }
  }
  if (STATS) {
    int chunk = blockIdx.y * 4 + w;
#pragma unroll
    for (int i = 0; i < 2; i++)
#pragma unroll
      for (int r = 0; r < 4; r++) {
        float s = ps[i][r], q = pq[i][r];
        s += __shfl_xor(s, 1); q += __shfl_xor(q, 1);
        s += __shfl_xor(s, 2); q += __shfl_xor(q, 2);
        s += __shfl_xor(s, 4); q += __shfl_xor(q, 4);
        s += __shfl_xor(s, 8); q += __shfl_xor(q, 8);
        if (lc == 0) {
          int row = m0 + i * 16 + lg * 4 + r;
          Psum[row * 8 + chunk] = s;
          Psq[row * 8 + chunk] = q;
        }
      }
  }
}

// ---------------- fused QKV GEMM (same core), V written transposed ----------------
// grid (256, 6): n0 in 256-chunks over [Q|K|V] = 1536 cols.
__global__ __launch_bounds__(256) void qkv_kernel(const bf16_t* __restrict__ A,
                                                  const bf16_t* __restrict__ Wqkv,
                                                  const float* __restrict__ bq,
                                                  const float* __restrict__ bk,
                                                  const float* __restrict__ bv,
                                                  bf16_t* __restrict__ QB,
                                                  bf16_t* __restrict__ KB,
                                                  bf16_t* __restrict__ VT) {
  __shared__ __align__(16) bf16_t As[2][32 * 64];
  __shared__ __align__(16) bf16_t Bs[2][256 * 64];
  int tid = threadIdx.x;
  int w = tid >> 6, l = tid & 63;
  int m0 = blockIdx.x * 32, n0 = blockIdx.y * 256;
  int sec = n0 >> 9;  // 0=Q 1=K 2=V (256-chunks never cross 512 boundaries)
  int lc = l & 15, lg = l >> 4;
  int srow = l >> 3, scb = (l & 7) * 16;
  f32x4 acc[2][4];
#pragma unroll
  for (int i = 0; i < 2; i++)
#pragma unroll
    for (int j = 0; j < 4; j++) acc[i][j] = f32x4{0.f, 0.f, 0.f, 0.f};

  GEMM_STAGE(A, Wqkv, 0, 0);
  __syncthreads();
  int cur = 0;
  for (int t = 0; t < 8; t++) {
    if (t < 7) GEMM_STAGE(A, Wqkv, cur ^ 1, (t + 1) * 64);
    GEMM_COMPUTE(cur);
    __syncthreads();
    cur ^= 1;
  }

  const float* bp = (sec == 0) ? bq : (sec == 1) ? bk : bv;
#pragma unroll
  for (int i = 0; i < 2; i++) {
    int mbase = m0 + i * 16 + lg * 4;
#pragma unroll
    for (int j = 0; j < 4; j++) {
      int n = n0 + w * 64 + j * 16 + lc;
      int nl = n & 511;
      float bn = bp[nl];
      if (sec < 2) {
        bf16_t* ob = (sec == 0) ? QB : KB;
#pragma unroll
        for (int r = 0; r < 4; r++)
          ob[(size_t)(mbase + r) * CCH + nl] = (bf16_t)(acc[i][j][r] + bn);
      } else {
        int h = nl >> 6, d = nl & 63;
        int b = mbase >> 10, lpos = mbase & 1023;
        bf16x4 t;
#pragma unroll
        for (int r = 0; r < 4; r++) t[r] = (bf16_t)(acc[i][j][r] + bn);
        *(bf16x4*)&VT[(((size_t)(b * 8 + h) * 64 + d) * L_SEQ) + lpos] = t;
      }
    }
  }
}

// ---------------- flash attention v5: QBLK=128, double-buffered K/V ----------------
// grid 512 = qb(8) x h(8) x b(8), XCD-contiguous (one batch per XCD).
#define ATT_STAGE(BI, KC)                                                         \
  do {                                                                            \
    _Pragma("unroll") for (int r = 0; r < 2; r++) {                               \
      int row = r * 32 + w * 8 + srow;                                            \
      int sc = (scb ^ ((row & 7) << 4)) >> 1;                                     \
      int key = (KC) * 64 + row;                                                  \
      gload_lds16(K + ((size_t)(b * L_SEQ + key) * CCH + h * 64 + sc),            \
                  &Ks[BI][(r * 32 + w * 8) * 64]);                                \
      gload_lds16(VT + (((size_t)(b * 8 + h) * 64 + row) * L_SEQ + (KC) * 64 + sc),\
                  &Vs[BI][(r * 32 + w * 8) * 64]);                                \
    }                                                                             \
  } while (0)

__global__ __launch_bounds__(256) void attn_kernel(const bf16_t* __restrict__ Q,
                                                   const bf16_t* __restrict__ K,
                                                   const bf16_t* __restrict__ VT,
                                                   const float* __restrict__ mask,
                                                   bf16_t* __restrict__ O) {
  __shared__ __align__(16) bf16_t Ks[2][64 * 64];
  __shared__ __align__(16) bf16_t Vs[2][64 * 64];
  __shared__ __align__(16) bf16_t Pl[4][16 * 64];
  int tid = threadIdx.x;
  int w = tid >> 6, l = tid & 63;
  int bid = blockIdx.x;
  int sw = (bid & 7) * 64 + (bid >> 3);
  int qb = sw & 7, h = (sw >> 3) & 7, b = sw >> 6;
  int lg = l >> 4, lc = l & 15;

  bf16x8 qf[2][2];
#pragma unroll
  for (int s = 0; s < 2; s++) {
    int qrow = qb * 128 + s * 64 + w * 16 + lc;
    const bf16_t* qptr = Q + ((size_t)(b * L_SEQ + qrow) * CCH + h * 64);
    qf[s][0] = *(const bf16x8*)(qptr + lg * 8);
    qf[s][1] = *(const bf16x8*)(qptr + 32 + lg * 8);
  }

  f32x4 oacc[2][4];
  float psl[2][4];
#pragma unroll
  for (int s = 0; s < 2; s++)
#pragma unroll
    for (int nf = 0; nf < 4; nf++) {
      oacc[s][nf] = f32x4{0.f, 0.f, 0.f, 0.f};
      psl[s][nf] = 0.f;
    }

  int srow = l >> 3;
  int scb = (l & 7) * 16;

  ATT_STAGE(0, 0);
  __syncthreads();
  int cur = 0;
  for (int kc = 0; kc < 16; kc++) {
    if (kc < 15) ATT_STAGE(cur ^ 1, kc + 1);

    float mv[4];
#pragma unroll
    for (int kf = 0; kf < 4; kf++) mv[kf] = mask[b * L_SEQ + kc * 64 + kf * 16 + lc];

#pragma unroll
    for (int s = 0; s < 2; s++) {
      f32x4 sacc[4];
#pragma unroll
      for (int kf = 0; kf < 4; kf++) sacc[kf] = f32x4{0.f, 0.f, 0.f, 0.f};
      __builtin_amdgcn_s_setprio(1);
#pragma unroll
      for (int kf = 0; kf < 4; kf++) {
        int row = kf * 16 + lc;
        int sx = (row & 7) << 4;
        const bf16_t* kr = &Ks[cur][row * 64];
        bf16x8 b0 = *(const bf16x8*)(kr + (((lg * 16) ^ sx) >> 1));
        sacc[kf] = __builtin_amdgcn_mfma_f32_16x16x32_bf16(qf[s][0], b0, sacc[kf], 0, 0, 0);
        bf16x8 b1 = *(const bf16x8*)(kr + (((64 + lg * 16) ^ sx) >> 1));
        sacc[kf] = __builtin_amdgcn_mfma_f32_16x16x32_bf16(qf[s][1], b1, sacc[kf], 0, 0, 0);
      }
      __builtin_amdgcn_s_setprio(0);

      // P = exp(S*scale) with mask; no max subtraction (scores bounded),
      // exact softmax after final normalization. Masked: exp(-1e30)=0.
#pragma unroll
      for (int kf = 0; kf < 4; kf++) {
        float mneg = (1.f - mv[kf]) * (-1e30f);
        float msc = 0.125f * mv[kf];
#pragma unroll
        for (int j = 0; j < 4; j++) {
          float p = __expf(sacc[kf][j] * msc + mneg);
          psl[s][j] += p;
          int q = lg * 4 + j;
          int cb = (kf * 32 + lc * 2) ^ ((q & 7) << 4);
          Pl[w][(q * 128 + cb) >> 1] = (bf16_t)p;
        }
      }

      int sp = (lc & 7) << 4;
      bf16x8 pa0 = *(const bf16x8*)&Pl[w][(lc * 128 + ((lg * 16) ^ sp)) >> 1];
      bf16x8 pa1 = *(const bf16x8*)&Pl[w][(lc * 128 + ((64 + lg * 16) ^ sp)) >> 1];
      __builtin_amdgcn_s_setprio(1);
#pragma unroll
      for (int nf = 0; nf < 4; nf++) {
        int d = nf * 16 + lc;
        int sx = (d & 7) << 4;
        const bf16_t* vr = &Vs[cur][d * 64];
        bf16x8 vb0 = *(const bf16x8*)(vr + (((lg * 16) ^ sx) >> 1));
        oacc[s][nf] = __builtin_amdgcn_mfma_f32_16x16x32_bf16(pa0, vb0, oacc[s][nf], 0, 0, 0);
        bf16x8 vb1 = *(const bf16x8*)(vr + (((64 + lg * 16) ^ sx) >> 1));
        oacc[s][nf] = __builtin_amdgcn_mfma_f32_16x16x32_bf16(pa1, vb1, oacc[s][nf], 0, 0, 0);
      }
      __builtin_amdgcn_s_setprio(0);
    }
    __syncthreads();
    cur ^= 1;
  }

#pragma unroll
  for (int off = 1; off < 16; off <<= 1)
#pragma unroll
    for (int s = 0; s < 2; s++)
#pragma unroll
      for (int j = 0; j < 4; j++) psl[s][j] += __shfl_xor(psl[s][j], off);

#pragma unroll
  for (int s = 0; s < 2; s++)
#pragma unroll
    for (int j = 0; j < 4; j++) {
      float is = 1.0f / psl[s][j];
      int r = qb * 128 + s * 64 + w * 16 + lg * 4 + j;
      bf16_t* op = O + ((size_t)(b * L_SEQ + r) * CCH + h * 64);
#pragma unroll
      for (int nf = 0; nf < 4; nf++) op[nf * 16 + lc] = (bf16_t)(oacc[s][nf][j] * is);
    }
}

// ---------------- launcher ----------------
extern "C" void kernel_launch(void* const* d_in, const int* in_sizes, int n_in,
                              void* d_out, int out_size, void* d_ws, size_t ws_size,
                              hipStream_t stream) {
  const float* x = (const float*)d_in[0];
  const float* mask = (const float*)d_in[1];
  const float* dw_w = (const float*)d_in[2];
  const float* dw_b = (const float*)d_in[3];
  const float* pw_w = (const float*)d_in[4];
  const float* pw_b = (const float*)d_in[5];
  const float* ln_conv_g = (const float*)d_in[6];
  const float* ln_conv_b = (const float*)d_in[7];
  const float* Wq = (const float*)d_in[8];  const float* bq = (const float*)d_in[9];
  const float* Wk = (const float*)d_in[10]; const float* bk = (const float*)d_in[11];
  const float* Wv = (const float*)d_in[12]; const float* bv = (const float*)d_in[13];
  const float* Wo = (const float*)d_in[14]; const float* bo = (const float*)d_in[15];
  const float* ln_att_g = (const float*)d_in[16]; const float* ln_att_b = (const float*)d_in[17];
  const float* Wf = (const float*)d_in[18]; const float* bfc = (const float*)d_in[19];
  const float* ln_fc_g = (const float*)d_in[20]; const float* ln_fc_b = (const float*)d_in[21];

  float* OUT = (float*)d_out;  // fp32 residual chain

  char* ws = (char*)d_ws;
  bf16_t* ABF  = (bf16_t*)(ws);                      // 8 MiB
  bf16_t* QB   = (bf16_t*)(ws + (8u << 20));         // 8 MiB
  bf16_t* KB   = (bf16_t*)(ws + (16u << 20));        // 8 MiB
  bf16_t* VT   = (bf16_t*)(ws + (24u << 20));        // 8 MiB  [b][h][d][key]
  char*   wb   = ws + (32u << 20);
  bf16_t* WPW  = (bf16_t*)(wb);                      // 2 MiB
  bf16_t* WQKV = (bf16_t*)(wb + (2u << 20));         // 1.5 MiB
  bf16_t* WOB  = (bf16_t*)(wb + 3584u * 1024);       // 0.5 MiB
  bf16_t* WFB  = (bf16_t*)(wb + (4u << 20));         // 0.5 MiB
  float*  WT   = (float*)(wb + 4608u * 1024);        // 56 KiB
  float*  PET  = (float*)(ws + (37u << 20));         // 2 MiB
  float*  Psum = (float*)(ws + (39u << 20));         // 256 KiB
  float*  Psq  = (float*)(ws + (39u << 20) + 262144);// 256 KiB

  cvtall_kernel<<<11320, 256, 0, stream>>>(pw_w, Wq, Wk, Wv, Wo, Wf, dw_w,
                                           WPW, WQKV, WOB, WFB, WT, PET);
  pe_kernel<<<dim3(32, 16, NB), dim3(32, 8), 0, stream>>>(x, PET, OUT);
  stats_kernel<<<2048, 256, 0, stream>>>(OUT, Psum, Psq);

  dim3 ggrid(256, 2);
  for (int i = 0; i < 4; i++) {
    dwln_kernel<<<2048, 256, 0, stream>>>(OUT, Psum, Psq, ln_conv_g + i * 512,
                                          ln_conv_b + i * 512, WT + i * 3584,
                                          dw_b + i * 512, ABF);
    gemm_kernel<1, 1, 0, 1><<<ggrid, 256, 0, stream>>>(ABF, WPW + i * 262144,
                                                       pw_b + i * 512, OUT, OUT,
                                                       nullptr, Psum, Psq);
  }
  // attention
  ln_apply_kernel<<<2048, 256, 0, stream>>>(OUT, Psum, Psq, ln_att_g, ln_att_b, ABF);
  qkv_kernel<<<dim3(256, 6), 256, 0, stream>>>(ABF, WQKV, bq, bk, bv, QB, KB, VT);
  attn_kernel<<<512, 256, 0, stream>>>(QB, KB, VT, mask, ABF);
  gemm_kernel<0, 1, 0, 1><<<ggrid, 256, 0, stream>>>(ABF, WOB, bo, OUT, OUT,
                                                     nullptr, Psum, Psq);
  // FC
  ln_apply_kernel<<<2048, 256, 0, stream>>>(OUT, Psum, Psq, ln_fc_g, ln_fc_b, ABF);
  gemm_kernel<1, 1, 0, 0><<<ggrid, 256, 0, stream>>>(ABF, WFB, bfc, OUT,
                                                     (float*)d_out, nullptr,
                                                     nullptr, nullptr);
}

// Round 10
// 353.022 us; speedup vs baseline: 1.0175x; 1.0175x over previous
//
#include <hip/hip_runtime.h>
#include <hip/hip_bf16.h>

#define L_SEQ 1024
#define CCH   512
#define NB    8

typedef __bf16 bf16_t;
typedef __bf16 bf16x4 __attribute__((ext_vector_type(4)));
typedef __bf16 bf16x8 __attribute__((ext_vector_type(8)));
typedef float  f32x4  __attribute__((ext_vector_type(4)));

__device__ __forceinline__ void gload_lds16(const void* g, void* l) {
  __builtin_amdgcn_global_load_lds((const __attribute__((address_space(1))) void*)g,
                                   (__attribute__((address_space(3))) void*)l, 16, 0, 0);
}

// ======== prep: PE+transpose (+LN partials) AND all weight conversions ========
// blocks [0,4096): pe tiles; [4096, 15416): weight cvt + PE table.
__global__ __launch_bounds__(256) void prep_kernel(
    const float* __restrict__ x, const float* __restrict__ PET_in,
    const float* __restrict__ pw_w, const float* __restrict__ Wq,
    const float* __restrict__ Wk, const float* __restrict__ Wv,
    const float* __restrict__ Wo, const float* __restrict__ Wf,
    const float* __restrict__ dw_w,
    bf16_t* __restrict__ WPW, bf16_t* __restrict__ WQKV,
    bf16_t* __restrict__ WOB, bf16_t* __restrict__ WFB,
    float* __restrict__ WT, float* __restrict__ PET,
    float* __restrict__ out, float* __restrict__ Psum, float* __restrict__ Psq) {
  int blk = blockIdx.x;
  if (blk < 4096) {
    __shared__ float tile[32][33];
    int bx = blk & 31, by = (blk >> 5) & 15, b = blk >> 9;
    int l0 = bx * 32, c0 = by * 32;
    int tx = threadIdx.x & 31, ty = threadIdx.x >> 5;
#pragma unroll
    for (int r = 0; r < 32; r += 8)
      tile[ty + r][tx] = x[(size_t)(b * CCH + c0 + ty + r) * L_SEQ + l0 + tx];
    __syncthreads();
#pragma unroll
    for (int r = 0; r < 32; r += 8) {
      int l = l0 + ty + r, c = c0 + tx;
      // PET may not be ready on first call ordering; compute inline (cheap, once).
      float div = expf(-(float)(2 * (c >> 1)) * (9.210340371976184f / 512.0f));
      float ang = (float)l * div;
      float pe = (c & 1) ? cosf(ang) : sinf(ang);
      float v = tile[tx][ty + r] + pe;
      out[(size_t)(b * L_SEQ + l) * CCH + c] = v;
      float s = v, q = v * v;
#pragma unroll
      for (int off = 1; off < 32; off <<= 1) {
        s += __shfl_xor(s, off);
        q += __shfl_xor(q, off);
      }
      if (tx == 0) {
        size_t row = (size_t)(b * L_SEQ + l);
        Psum[row * 16 + (c0 >> 5)] = s;
        Psq[row * 16 + (c0 >> 5)] = q;
      }
    }
    return;
  }
  int idx = (blk - 4096) * 256 + threadIdx.x;
  if (idx < 1048576) { WPW[idx] = (bf16_t)pw_w[idx]; return; }
  idx -= 1048576;
  if (idx < 262144) { WQKV[idx] = (bf16_t)Wq[idx]; return; }
  idx -= 262144;
  if (idx < 262144) { WQKV[262144 + idx] = (bf16_t)Wk[idx]; return; }
  idx -= 262144;
  if (idx < 262144) { WQKV[524288 + idx] = (bf16_t)Wv[idx]; return; }
  idx -= 262144;
  if (idx < 262144) { WOB[idx] = (bf16_t)Wo[idx]; return; }
  idx -= 262144;
  if (idx < 262144) { WFB[idx] = (bf16_t)Wf[idx]; return; }
  idx -= 262144;
  if (idx < 14336) {  // dw weights transpose [i][c][t] -> [i][t][c], fp32
    int i = idx / 3584, r = idx % 3584, t = r >> 9, c = r & 511;
    WT[idx] = dw_w[i * 3584 + c * 7 + t];
  }
  (void)PET_in; (void)PET;
}

// ---------------- LN apply (16-chunk partials) -> bf16 ----------------
__global__ __launch_bounds__(256) void ln_apply_kernel(const float* __restrict__ in,
                                                       const float* __restrict__ Psum,
                                                       const float* __restrict__ Psq,
                                                       const float* __restrict__ gam,
                                                       const float* __restrict__ bet,
                                                       bf16_t* __restrict__ out) {
  int w = threadIdx.x >> 6, l = threadIdx.x & 63;
  int row = blockIdx.x * 4 + w;
  float v0 = 0.f;
  if (l < 16) v0 = Psum[(size_t)row * 16 + l];
  else if (l < 32) v0 = Psq[(size_t)row * 16 + (l - 16)];
  v0 += __shfl_xor(v0, 1); v0 += __shfl_xor(v0, 2);
  v0 += __shfl_xor(v0, 4); v0 += __shfl_xor(v0, 8);
  float sum = __shfl(v0, 0), sq = __shfl(v0, 16);
  float mean = sum * (1.0f / 512.0f);
  float var = sq * (1.0f / 512.0f) - mean * mean;
  float inv = rsqrtf(var + 1e-5f);
  const float* p = in + (size_t)row * CCH + l * 8;
  float v[8], gv[8], bv[8];
  *(float4*)(&v[0]) = *(const float4*)p;
  *(float4*)(&v[4]) = *(const float4*)(p + 4);
  *(float4*)(&gv[0]) = *(const float4*)(gam + l * 8);
  *(float4*)(&gv[4]) = *(const float4*)(gam + l * 8 + 4);
  *(float4*)(&bv[0]) = *(const float4*)(bet + l * 8);
  *(float4*)(&bv[4]) = *(const float4*)(bet + l * 8 + 4);
  bf16x8 o;
#pragma unroll
  for (int j = 0; j < 8; j++) o[j] = (bf16_t)((v[j] - mean) * inv * gv[j] + bv[j]);
  *(bf16x8*)(out + (size_t)row * CCH + l * 8) = o;
}

// ---------------- fused LN + depthwise conv K=7 (16-chunk partials) ----------------
__global__ __launch_bounds__(256) void dwln_kernel(const float* __restrict__ in,
                                                   const float* __restrict__ Psum,
                                                   const float* __restrict__ Psq,
                                                   const float* __restrict__ gam,
                                                   const float* __restrict__ bet,
                                                   const float* __restrict__ wtt,  // [7][512]
                                                   const float* __restrict__ dbias,
                                                   bf16_t* __restrict__ out) {
  int idx = blockIdx.x * 256 + threadIdx.x;
  int lane = threadIdx.x & 63;  // == channel group cg
  int row = idx >> 6;
  int l = row & (L_SEQ - 1);
  float m_ = 0.f, i_ = 0.f;
  if (lane < 7) {
    int ll = l + lane - 3;
    if (ll >= 0 && ll < L_SEQ) {
      int rr = row + lane - 3;
      float s = 0.f, q = 0.f;
#pragma unroll
      for (int c = 0; c < 16; c++) { s += Psum[(size_t)rr * 16 + c]; q += Psq[(size_t)rr * 16 + c]; }
      float mm = s * (1.0f / 512.0f);
      m_ = mm;
      i_ = rsqrtf(q * (1.0f / 512.0f) - mm * mm + 1e-5f);
    }
  }
  float gv[8], bv[8], acc[8];
  *(float4*)&gv[0] = *(const float4*)(gam + lane * 8);
  *(float4*)&gv[4] = *(const float4*)(gam + lane * 8 + 4);
  *(float4*)&bv[0] = *(const float4*)(bet + lane * 8);
  *(float4*)&bv[4] = *(const float4*)(bet + lane * 8 + 4);
  *(float4*)&acc[0] = *(const float4*)(dbias + lane * 8);
  *(float4*)&acc[4] = *(const float4*)(dbias + lane * 8 + 4);
#pragma unroll
  for (int t = 0; t < 7; t++) {
    float mt = __shfl(m_, t), it = __shfl(i_, t);
    int ll = l + t - 3;
    if (ll >= 0 && ll < L_SEQ) {
      const float* p = in + (size_t)(row + t - 3) * CCH + lane * 8;
      float v[8], wv[8];
      *(float4*)&v[0] = *(const float4*)p;
      *(float4*)&v[4] = *(const float4*)(p + 4);
      *(float4*)&wv[0] = *(const float4*)(wtt + t * CCH + lane * 8);
      *(float4*)&wv[4] = *(const float4*)(wtt + t * CCH + lane * 8 + 4);
#pragma unroll
      for (int j = 0; j < 8; j++)
        acc[j] += ((v[j] - mt) * it * gv[j] + bv[j]) * wv[j];
    }
  }
  bf16x8 o;
#pragma unroll
  for (int j = 0; j < 8; j++) o[j] = (bf16_t)acc[j];
  *(bf16x8*)&out[(size_t)row * CCH + lane * 8] = o;
}

// ======== GEMM core (r7 shape): BM=64 BN=128 BK=64, dbuf, 3 blocks/CU ========
#define GSTAGE64(SRCA, SRCB, BI, K0)                                              \
  do {                                                                            \
    _Pragma("unroll") for (int cc = 0; cc < 2; cc++) {                            \
      int row_ = cc * 32 + w * 8 + srow;                                          \
      int off_ = (scb ^ ((row_ & 7) << 4)) >> 1;                                  \
      gload_lds16(SRCA + (size_t)(m0 + row_) * CCH + (K0) + off_,                 \
                  &As[BI][(cc * 32 + w * 8) * 64]);                               \
    }                                                                             \
    _Pragma("unroll") for (int cc = 0; cc < 4; cc++) {                            \
      int row_ = cc * 32 + w * 8 + srow;                                          \
      int off_ = (scb ^ ((row_ & 7) << 4)) >> 1;                                  \
      gload_lds16(SRCB + (size_t)(n0 + row_) * CCH + (K0) + off_,                 \
                  &Bs[BI][(cc * 32 + w * 8) * 64]);                               \
    }                                                                             \
  } while (0)

#define GCOMP64(BI)                                                               \
  do {                                                                            \
    __builtin_amdgcn_s_setprio(1);                                                \
    _Pragma("unroll") for (int ks = 0; ks < 2; ks++) {                            \
      bf16x8 fa[2], fb[4];                                                        \
      _Pragma("unroll") for (int i = 0; i < 2; i++) {                             \
        int ra = wr * 32 + i * 16 + lc;                                           \
        fa[i] = *(const bf16x8*)&As[BI][ra * 64 +                                 \
                 (((ks * 64 + lg * 16) ^ ((ra & 7) << 4)) >> 1)];                 \
      }                                                                           \
      _Pragma("unroll") for (int j = 0; j < 4; j++) {                             \
        int rb = wc * 64 + j * 16 + lc;                                           \
        fb[j] = *(const bf16x8*)&Bs[BI][rb * 64 +                                 \
                 (((ks * 64 + lg * 16) ^ ((rb & 7) << 4)) >> 1)];                 \
      }                                                                           \
      _Pragma("unroll") for (int i = 0; i < 2; i++)                               \
        _Pragma("unroll") for (int j = 0; j < 4; j++)                             \
          acc[i][j] = __builtin_amdgcn_mfma_f32_16x16x32_bf16(fa[i], fb[j],       \
                                                              acc[i][j], 0, 0, 0);\
    }                                                                             \
    __builtin_amdgcn_s_setprio(0);                                                \
  } while (0)

// out[m,n] = A[m,:] . W[n,:] (+bias, relu, res); optional 32-col LN partials.
// grid (M/64, N/128)
template <int RELU, int RES, int BF16OUT, int STATS>
__global__ __launch_bounds__(256) void gemm_kernel(const bf16_t* __restrict__ A,
                                                   const bf16_t* __restrict__ W,
                                                   const float* __restrict__ bias,
                                                   const float* __restrict__ res,
                                                   float* __restrict__ outf,
                                                   bf16_t* __restrict__ outb,
                                                   float* __restrict__ Psum,
                                                   float* __restrict__ Psq) {
  __shared__ __align__(16) bf16_t As[2][64 * 64];
  __shared__ __align__(16) bf16_t Bs[2][128 * 64];
  int tid = threadIdx.x;
  int w = tid >> 6, l = tid & 63;
  int m0 = blockIdx.x * 64, n0 = blockIdx.y * 128;
  int wr = w >> 1, wc = w & 1;
  int lc = l & 15, lg = l >> 4;
  int srow = l >> 3, scb = (l & 7) * 16;
  f32x4 acc[2][4];
#pragma unroll
  for (int i = 0; i < 2; i++)
#pragma unroll
    for (int j = 0; j < 4; j++) acc[i][j] = f32x4{0.f, 0.f, 0.f, 0.f};

  GSTAGE64(A, W, 0, 0);
  __syncthreads();
  int cur = 0;
  for (int t = 0; t < 8; t++) {
    if (t < 7) GSTAGE64(A, W, cur ^ 1, (t + 1) * 64);
    GCOMP64(cur);
    __syncthreads();
    cur ^= 1;
  }

#pragma unroll
  for (int i = 0; i < 2; i++) {
    int mbase = m0 + wr * 32 + i * 16 + lg * 4;
    float ps[2][4], pq[2][4];
    if (STATS) {
#pragma unroll
      for (int jh = 0; jh < 2; jh++)
#pragma unroll
        for (int r = 0; r < 4; r++) { ps[jh][r] = 0.f; pq[jh][r] = 0.f; }
    }
#pragma unroll
    for (int j = 0; j < 4; j++) {
      int n = n0 + wc * 64 + j * 16 + lc;
      float bn = bias[n];
#pragma unroll
      for (int r = 0; r < 4; r++) {
        int m = mbase + r;
        float v2 = acc[i][j][r] + bn;
        if (RELU) v2 = fmaxf(v2, 0.f);
        if (RES) v2 += res[(size_t)m * CCH + n];
        if (BF16OUT) outb[(size_t)m * CCH + n] = (bf16_t)v2;
        else outf[(size_t)m * CCH + n] = v2;
        if (STATS) { ps[j >> 1][r] += v2; pq[j >> 1][r] += v2 * v2; }
      }
    }
    if (STATS) {
#pragma unroll
      for (int jh = 0; jh < 2; jh++)
#pragma unroll
        for (int r = 0; r < 4; r++) {
          float s = ps[jh][r], q = pq[jh][r];
          s += __shfl_xor(s, 1); q += __shfl_xor(q, 1);
          s += __shfl_xor(s, 2); q += __shfl_xor(q, 2);
          s += __shfl_xor(s, 4); q += __shfl_xor(q, 4);
          s += __shfl_xor(s, 8); q += __shfl_xor(q, 8);
          if (lc == 0) {
            size_t row = mbase + r;
            Psum[row * 16 + blockIdx.y * 4 + wc * 2 + jh] = s;
            Psq[row * 16 + blockIdx.y * 4 + wc * 2 + jh] = q;
          }
        }
    }
  }
}

// ======== qkv core: BM=32 BN=256 BK=64 (unchanged from r9) ========
#define GEMM_STAGE(SRCA, SRCB, BI, K0)                                            \
  do {                                                                            \
    {                                                                             \
      int row_ = w * 8 + srow;                                                    \
      int off_ = (scb ^ ((row_ & 7) << 4)) >> 1;                                  \
      gload_lds16(SRCA + (size_t)(m0 + row_) * CCH + (K0) + off_,                 \
                  &As[BI][(w * 8) * 64]);                                         \
    }                                                                             \
    _Pragma("unroll") for (int cc = 0; cc < 8; cc++) {                            \
      int row_ = cc * 32 + w * 8 + srow;                                          \
      int off_ = (scb ^ ((row_ & 7) << 4)) >> 1;                                  \
      gload_lds16(SRCB + (size_t)(n0 + row_) * CCH + (K0) + off_,                 \
                  &Bs[BI][(cc * 32 + w * 8) * 64]);                               \
    }                                                                             \
  } while (0)

#define GEMM_COMPUTE(BI)                                                          \
  do {                                                                            \
    __builtin_amdgcn_s_setprio(1);                                                \
    _Pragma("unroll") for (int ks = 0; ks < 2; ks++) {                            \
      bf16x8 fa[2], fb[4];                                                        \
      _Pragma("unroll") for (int i = 0; i < 2; i++) {                             \
        int ra = i * 16 + lc;                                                     \
        fa[i] = *(const bf16x8*)&As[BI][ra * 64 +                                 \
                 (((ks * 64 + lg * 16) ^ ((ra & 7) << 4)) >> 1)];                 \
      }                                                                           \
      _Pragma("unroll") for (int j = 0; j < 4; j++) {                             \
        int rb = w * 64 + j * 16 + lc;                                            \
        fb[j] = *(const bf16x8*)&Bs[BI][rb * 64 +                                 \
                 (((ks * 64 + lg * 16) ^ ((rb & 7) << 4)) >> 1)];                 \
      }                                                                           \
      _Pragma("unroll") for (int i = 0; i < 2; i++)                               \
        _Pragma("unroll") for (int j = 0; j < 4; j++)                             \
          acc[i][j] = __builtin_amdgcn_mfma_f32_16x16x32_bf16(fa[i], fb[j],       \
                                                              acc[i][j], 0, 0, 0);\
    }                                                                             \
    __builtin_amdgcn_s_setprio(0);                                                \
  } while (0)

// grid (256, 6): n0 in 256-chunks over [Q|K|V] = 1536 cols.
__global__ __launch_bounds__(256) void qkv_kernel(const bf16_t* __restrict__ A,
                                                  const bf16_t* __restrict__ Wqkv,
                                                  const float* __restrict__ bq,
                                                  const float* __restrict__ bk,
                                                  const float* __restrict__ bv,
                                                  bf16_t* __restrict__ QB,
                                                  bf16_t* __restrict__ KB,
                                                  bf16_t* __restrict__ VT) {
  __shared__ __align__(16) bf16_t As[2][32 * 64];
  __shared__ __align__(16) bf16_t Bs[2][256 * 64];
  int tid = threadIdx.x;
  int w = tid >> 6, l = tid & 63;
  int m0 = blockIdx.x * 32, n0 = blockIdx.y * 256;
  int sec = n0 >> 9;
  int lc = l & 15, lg = l >> 4;
  int srow = l >> 3, scb = (l & 7) * 16;
  f32x4 acc[2][4];
#pragma unroll
  for (int i = 0; i < 2; i++)
#pragma unroll
    for (int j = 0; j < 4; j++) acc[i][j] = f32x4{0.f, 0.f, 0.f, 0.f};

  GEMM_STAGE(A, Wqkv, 0, 0);
  __syncthreads();
  int cur = 0;
  for (int t = 0; t < 8; t++) {
    if (t < 7) GEMM_STAGE(A, Wqkv, cur ^ 1, (t + 1) * 64);
    GEMM_COMPUTE(cur);
    __syncthreads();
    cur ^= 1;
  }

  const float* bp = (sec == 0) ? bq : (sec == 1) ? bk : bv;
#pragma unroll
  for (int i = 0; i < 2; i++) {
    int mbase = m0 + i * 16 + lg * 4;
#pragma unroll
    for (int j = 0; j < 4; j++) {
      int n = n0 + w * 64 + j * 16 + lc;
      int nl = n & 511;
      float bn = bp[nl];
      if (sec < 2) {
        bf16_t* ob = (sec == 0) ? QB : KB;
#pragma unroll
        for (int r = 0; r < 4; r++)
          ob[(size_t)(mbase + r) * CCH + nl] = (bf16_t)(acc[i][j][r] + bn);
      } else {
        int h = nl >> 6, d = nl & 63;
        int b = mbase >> 10, lpos = mbase & 1023;
        bf16x4 t;
#pragma unroll
        for (int r = 0; r < 4; r++) t[r] = (bf16_t)(acc[i][j][r] + bn);
        *(bf16x4*)&VT[(((size_t)(b * 8 + h) * 64 + d) * L_SEQ) + lpos] = t;
      }
    }
  }
}

// ---------------- flash attention (r9: QBLK=128, dbuf K/V, setprio) ----------------
#define ATT_STAGE(BI, KC)                                                         \
  do {                                                                            \
    _Pragma("unroll") for (int r = 0; r < 2; r++) {                               \
      int row = r * 32 + w * 8 + srow;                                            \
      int sc = (scb ^ ((row & 7) << 4)) >> 1;                                     \
      int key = (KC) * 64 + row;                                                  \
      gload_lds16(K + ((size_t)(b * L_SEQ + key) * CCH + h * 64 + sc),            \
                  &Ks[BI][(r * 32 + w * 8) * 64]);                                \
      gload_lds16(VT + (((size_t)(b * 8 + h) * 64 + row) * L_SEQ + (KC) * 64 + sc),\
                  &Vs[BI][(r * 32 + w * 8) * 64]);                                \
    }                                                                             \
  } while (0)

__global__ __launch_bounds__(256) void attn_kernel(const bf16_t* __restrict__ Q,
                                                   const bf16_t* __restrict__ K,
                                                   const bf16_t* __restrict__ VT,
                                                   const float* __restrict__ mask,
                                                   bf16_t* __restrict__ O) {
  __shared__ __align__(16) bf16_t Ks[2][64 * 64];
  __shared__ __align__(16) bf16_t Vs[2][64 * 64];
  __shared__ __align__(16) bf16_t Pl[4][16 * 64];
  int tid = threadIdx.x;
  int w = tid >> 6, l = tid & 63;
  int bid = blockIdx.x;
  int sw = (bid & 7) * 64 + (bid >> 3);
  int qb = sw & 7, h = (sw >> 3) & 7, b = sw >> 6;
  int lg = l >> 4, lc = l & 15;

  bf16x8 qf[2][2];
#pragma unroll
  for (int s = 0; s < 2; s++) {
    int qrow = qb * 128 + s * 64 + w * 16 + lc;
    const bf16_t* qptr = Q + ((size_t)(b * L_SEQ + qrow) * CCH + h * 64);
    qf[s][0] = *(const bf16x8*)(qptr + lg * 8);
    qf[s][1] = *(const bf16x8*)(qptr + 32 + lg * 8);
  }

  f32x4 oacc[2][4];
  float psl[2][4];
#pragma unroll
  for (int s = 0; s < 2; s++)
#pragma unroll
    for (int nf = 0; nf < 4; nf++) {
      oacc[s][nf] = f32x4{0.f, 0.f, 0.f, 0.f};
      psl[s][nf] = 0.f;
    }

  int srow = l >> 3;
  int scb = (l & 7) * 16;

  ATT_STAGE(0, 0);
  __syncthreads();
  int cur = 0;
  for (int kc = 0; kc < 16; kc++) {
    if (kc < 15) ATT_STAGE(cur ^ 1, kc + 1);

    float mv[4];
#pragma unroll
    for (int kf = 0; kf < 4; kf++) mv[kf] = mask[b * L_SEQ + kc * 64 + kf * 16 + lc];

#pragma unroll
    for (int s = 0; s < 2; s++) {
      f32x4 sacc[4];
#pragma unroll
      for (int kf = 0; kf < 4; kf++) sacc[kf] = f32x4{0.f, 0.f, 0.f, 0.f};
      __builtin_amdgcn_s_setprio(1);
#pragma unroll
      for (int kf = 0; kf < 4; kf++) {
        int row = kf * 16 + lc;
        int sx = (row & 7) << 4;
        const bf16_t* kr = &Ks[cur][row * 64];
        bf16x8 b0 = *(const bf16x8*)(kr + (((lg * 16) ^ sx) >> 1));
        sacc[kf] = __builtin_amdgcn_mfma_f32_16x16x32_bf16(qf[s][0], b0, sacc[kf], 0, 0, 0);
        bf16x8 b1 = *(const bf16x8*)(kr + (((64 + lg * 16) ^ sx) >> 1));
        sacc[kf] = __builtin_amdgcn_mfma_f32_16x16x32_bf16(qf[s][1], b1, sacc[kf], 0, 0, 0);
      }
      __builtin_amdgcn_s_setprio(0);

#pragma unroll
      for (int kf = 0; kf < 4; kf++) {
        float mneg = (1.f - mv[kf]) * (-1e30f);
        float msc = 0.125f * mv[kf];
#pragma unroll
        for (int j = 0; j < 4; j++) {
          float p = __expf(sacc[kf][j] * msc + mneg);
          psl[s][j] += p;
          int q = lg * 4 + j;
          int cb = (kf * 32 + lc * 2) ^ ((q & 7) << 4);
          Pl[w][(q * 128 + cb) >> 1] = (bf16_t)p;
        }
      }

      int sp = (lc & 7) << 4;
      bf16x8 pa0 = *(const bf16x8*)&Pl[w][(lc * 128 + ((lg * 16) ^ sp)) >> 1];
      bf16x8 pa1 = *(const bf16x8*)&Pl[w][(lc * 128 + ((64 + lg * 16) ^ sp)) >> 1];
      __builtin_amdgcn_s_setprio(1);
#pragma unroll
      for (int nf = 0; nf < 4; nf++) {
        int d = nf * 16 + lc;
        int sx = (d & 7) << 4;
        const bf16_t* vr = &Vs[cur][d * 64];
        bf16x8 vb0 = *(const bf16x8*)(vr + (((lg * 16) ^ sx) >> 1));
        oacc[s][nf] = __builtin_amdgcn_mfma_f32_16x16x32_bf16(pa0, vb0, oacc[s][nf], 0, 0, 0);
        bf16x8 vb1 = *(const bf16x8*)(vr + (((64 + lg * 16) ^ sx) >> 1));
        oacc[s][nf] = __builtin_amdgcn_mfma_f32_16x16x32_bf16(pa1, vb1, oacc[s][nf], 0, 0, 0);
      }
      __builtin_amdgcn_s_setprio(0);
    }
    __syncthreads();
    cur ^= 1;
  }

#pragma unroll
  for (int off = 1; off < 16; off <<= 1)
#pragma unroll
    for (int s = 0; s < 2; s++)
#pragma unroll
      for (int j = 0; j < 4; j++) psl[s][j] += __shfl_xor(psl[s][j], off);

#pragma unroll
  for (int s = 0; s < 2; s++)
#pragma unroll
    for (int j = 0; j < 4; j++) {
      float is = 1.0f / psl[s][j];
      int r = qb * 128 + s * 64 + w * 16 + lg * 4 + j;
      bf16_t* op = O + ((size_t)(b * L_SEQ + r) * CCH + h * 64);
#pragma unroll
      for (int nf = 0; nf < 4; nf++) op[nf * 16 + lc] = (bf16_t)(oacc[s][nf][j] * is);
    }
}

// ---------------- launcher ----------------
extern "C" void kernel_launch(void* const* d_in, const int* in_sizes, int n_in,
                              void* d_out, int out_size, void* d_ws, size_t ws_size,
                              hipStream_t stream) {
  const float* x = (const float*)d_in[0];
  const float* mask = (const float*)d_in[1];
  const float* dw_w = (const float*)d_in[2];
  const float* dw_b = (const float*)d_in[3];
  const float* pw_w = (const float*)d_in[4];
  const float* pw_b = (const float*)d_in[5];
  const float* ln_conv_g = (const float*)d_in[6];
  const float* ln_conv_b = (const float*)d_in[7];
  const float* Wq = (const float*)d_in[8];  const float* bq = (const float*)d_in[9];
  const float* Wk = (const float*)d_in[10]; const float* bk = (const float*)d_in[11];
  const float* Wv = (const float*)d_in[12]; const float* bv = (const float*)d_in[13];
  const float* Wo = (const float*)d_in[14]; const float* bo = (const float*)d_in[15];
  const float* ln_att_g = (const float*)d_in[16]; const float* ln_att_b = (const float*)d_in[17];
  const float* Wf = (const float*)d_in[18]; const float* bfc = (const float*)d_in[19];
  const float* ln_fc_g = (const float*)d_in[20]; const float* ln_fc_b = (const float*)d_in[21];

  float* OUT = (float*)d_out;  // fp32 residual chain

  char* ws = (char*)d_ws;
  bf16_t* ABF  = (bf16_t*)(ws);                      // 8 MiB
  bf16_t* QB   = (bf16_t*)(ws + (8u << 20));         // 8 MiB
  bf16_t* KB   = (bf16_t*)(ws + (16u << 20));        // 8 MiB
  bf16_t* VT   = (bf16_t*)(ws + (24u << 20));        // 8 MiB  [b][h][d][key]
  char*   wb   = ws + (32u << 20);
  bf16_t* WPW  = (bf16_t*)(wb);                      // 2 MiB
  bf16_t* WQKV = (bf16_t*)(wb + (2u << 20));         // 1.5 MiB
  bf16_t* WOB  = (bf16_t*)(wb + 3584u * 1024);       // 0.5 MiB
  bf16_t* WFB  = (bf16_t*)(wb + (4u << 20));         // 0.5 MiB
  float*  WT   = (float*)(wb + 4608u * 1024);        // 56 KiB
  float*  PET  = (float*)(ws + (37u << 20));         // 2 MiB (unused)
  float*  Psum = (float*)(ws + (39u << 20));         // 512 KiB (16 chunks)
  float*  Psq  = (float*)(ws + (39u << 20) + 524288);// 512 KiB

  prep_kernel<<<15416, 256, 0, stream>>>(x, PET, pw_w, Wq, Wk, Wv, Wo, Wf, dw_w,
                                         WPW, WQKV, WOB, WFB, WT, PET,
                                         OUT, Psum, Psq);

  dim3 ggrid(128, 4);
  for (int i = 0; i < 4; i++) {
    dwln_kernel<<<2048, 256, 0, stream>>>(OUT, Psum, Psq, ln_conv_g + i * 512,
                                          ln_conv_b + i * 512, WT + i * 3584,
                                          dw_b + i * 512, ABF);
    gemm_kernel<1, 1, 0, 1><<<ggrid, 256, 0, stream>>>(ABF, WPW + i * 262144,
                                                       pw_b + i * 512, OUT, OUT,
                                                       nullptr, Psum, Psq);
  }
  // attention
  ln_apply_kernel<<<2048, 256, 0, stream>>>(OUT, Psum, Psq, ln_att_g, ln_att_b, ABF);
  qkv_kernel<<<dim3(256, 6), 256, 0, stream>>>(ABF, WQKV, bq, bk, bv, QB, KB, VT);
  attn_kernel<<<512, 256, 0, stream>>>(QB, KB, VT, mask, ABF);
  gemm_kernel<0, 1, 0, 1><<<ggrid, 256, 0, stream>>>(ABF, WOB, bo, OUT, OUT,
                                                     nullptr, Psum, Psq);
  // FC
  ln_apply_kernel<<<2048, 256, 0, stream>>>(OUT, Psum, Psq, ln_fc_g, ln_fc_b, ABF);
  gemm_kernel<1, 1, 0, 0><<<ggrid, 256, 0, stream>>>(ABF, WFB, bfc, OUT,
                                                     (float*)d_out, nullptr,
                                                     nullptr, nullptr);
}

// Round 11
// 334.251 us; speedup vs baseline: 1.0747x; 1.0562x over previous
//
#include <hip/hip_runtime.h>
#include <hip/hip_bf16.h>

#define L_SEQ 1024
#define CCH   512
#define NB    8

typedef __bf16 bf16_t;
typedef __bf16 bf16x4 __attribute__((ext_vector_type(4)));
typedef __bf16 bf16x8 __attribute__((ext_vector_type(8)));
typedef float  f32x4  __attribute__((ext_vector_type(4)));

__device__ __forceinline__ void gload_lds16(const void* g, void* l) {
  __builtin_amdgcn_global_load_lds((const __attribute__((address_space(1))) void*)g,
                                   (__attribute__((address_space(3))) void*)l, 16, 0, 0);
}

// ======== prep: PE+transpose (+LN partials, bf16 OUT) AND weight conversions ========
__global__ __launch_bounds__(256) void prep_kernel(
    const float* __restrict__ x,
    const float* __restrict__ pw_w, const float* __restrict__ Wq,
    const float* __restrict__ Wk, const float* __restrict__ Wv,
    const float* __restrict__ Wo, const float* __restrict__ Wf,
    const float* __restrict__ dw_w,
    bf16_t* __restrict__ WPW, bf16_t* __restrict__ WQKV,
    bf16_t* __restrict__ WOB, bf16_t* __restrict__ WFB,
    float* __restrict__ WT,
    bf16_t* __restrict__ out, float* __restrict__ Psum, float* __restrict__ Psq) {
  int blk = blockIdx.x;
  if (blk < 4096) {
    __shared__ float tile[32][33];
    int bx = blk & 31, by = (blk >> 5) & 15, b = blk >> 9;
    int l0 = bx * 32, c0 = by * 32;
    int tx = threadIdx.x & 31, ty = threadIdx.x >> 5;
#pragma unroll
    for (int r = 0; r < 32; r += 8)
      tile[ty + r][tx] = x[(size_t)(b * CCH + c0 + ty + r) * L_SEQ + l0 + tx];
    __syncthreads();
#pragma unroll
    for (int r = 0; r < 32; r += 8) {
      int l = l0 + ty + r, c = c0 + tx;
      float div = expf(-(float)(2 * (c >> 1)) * (9.210340371976184f / 512.0f));
      float ang = (float)l * div;
      float pe = (c & 1) ? cosf(ang) : sinf(ang);
      float v = tile[tx][ty + r] + pe;
      out[(size_t)(b * L_SEQ + l) * CCH + c] = (bf16_t)v;
      float s = v, q = v * v;
#pragma unroll
      for (int off = 1; off < 32; off <<= 1) {
        s += __shfl_xor(s, off);
        q += __shfl_xor(q, off);
      }
      if (tx == 0) {
        size_t row = (size_t)(b * L_SEQ + l);
        Psum[row * 16 + (c0 >> 5)] = s;
        Psq[row * 16 + (c0 >> 5)] = q;
      }
    }
    return;
  }
  int idx = (blk - 4096) * 256 + threadIdx.x;
  if (idx < 1048576) { WPW[idx] = (bf16_t)pw_w[idx]; return; }
  idx -= 1048576;
  if (idx < 262144) { WQKV[idx] = (bf16_t)Wq[idx]; return; }
  idx -= 262144;
  if (idx < 262144) { WQKV[262144 + idx] = (bf16_t)Wk[idx]; return; }
  idx -= 262144;
  if (idx < 262144) { WQKV[524288 + idx] = (bf16_t)Wv[idx]; return; }
  idx -= 262144;
  if (idx < 262144) { WOB[idx] = (bf16_t)Wo[idx]; return; }
  idx -= 262144;
  if (idx < 262144) { WFB[idx] = (bf16_t)Wf[idx]; return; }
  idx -= 262144;
  if (idx < 14336) {  // dw weights transpose [i][c][t] -> [i][t][c], fp32
    int i = idx / 3584, r = idx % 3584, t = r >> 9, c = r & 511;
    WT[idx] = dw_w[i * 3584 + c * 7 + t];
  }
}

// ---------------- LN apply (16-chunk partials), bf16 in -> bf16 out ----------------
__global__ __launch_bounds__(256) void ln_apply_kernel(const bf16_t* __restrict__ in,
                                                       const float* __restrict__ Psum,
                                                       const float* __restrict__ Psq,
                                                       const float* __restrict__ gam,
                                                       const float* __restrict__ bet,
                                                       bf16_t* __restrict__ out) {
  int w = threadIdx.x >> 6, l = threadIdx.x & 63;
  int row = blockIdx.x * 4 + w;
  float v0 = 0.f;
  if (l < 16) v0 = Psum[(size_t)row * 16 + l];
  else if (l < 32) v0 = Psq[(size_t)row * 16 + (l - 16)];
  v0 += __shfl_xor(v0, 1); v0 += __shfl_xor(v0, 2);
  v0 += __shfl_xor(v0, 4); v0 += __shfl_xor(v0, 8);
  float sum = __shfl(v0, 0), sq = __shfl(v0, 16);
  float mean = sum * (1.0f / 512.0f);
  float var = sq * (1.0f / 512.0f) - mean * mean;
  float inv = rsqrtf(var + 1e-5f);
  bf16x8 hv = *(const bf16x8*)(in + (size_t)row * CCH + l * 8);
  float gv[8], bv[8];
  *(float4*)(&gv[0]) = *(const float4*)(gam + l * 8);
  *(float4*)(&gv[4]) = *(const float4*)(gam + l * 8 + 4);
  *(float4*)(&bv[0]) = *(const float4*)(bet + l * 8);
  *(float4*)(&bv[4]) = *(const float4*)(bet + l * 8 + 4);
  bf16x8 o;
#pragma unroll
  for (int j = 0; j < 8; j++) o[j] = (bf16_t)(((float)hv[j] - mean) * inv * gv[j] + bv[j]);
  *(bf16x8*)(out + (size_t)row * CCH + l * 8) = o;
}

// ---------------- fused LN + depthwise conv K=7 (bf16 in) ----------------
__global__ __launch_bounds__(256) void dwln_kernel(const bf16_t* __restrict__ in,
                                                   const float* __restrict__ Psum,
                                                   const float* __restrict__ Psq,
                                                   const float* __restrict__ gam,
                                                   const float* __restrict__ bet,
                                                   const float* __restrict__ wtt,  // [7][512]
                                                   const float* __restrict__ dbias,
                                                   bf16_t* __restrict__ out) {
  int idx = blockIdx.x * 256 + threadIdx.x;
  int lane = threadIdx.x & 63;  // == channel group cg
  int row = idx >> 6;
  int l = row & (L_SEQ - 1);
  float m_ = 0.f, i_ = 0.f;
  if (lane < 7) {
    int ll = l + lane - 3;
    if (ll >= 0 && ll < L_SEQ) {
      int rr = row + lane - 3;
      float s = 0.f, q = 0.f;
#pragma unroll
      for (int c = 0; c < 16; c++) { s += Psum[(size_t)rr * 16 + c]; q += Psq[(size_t)rr * 16 + c]; }
      float mm = s * (1.0f / 512.0f);
      m_ = mm;
      i_ = rsqrtf(q * (1.0f / 512.0f) - mm * mm + 1e-5f);
    }
  }
  float gv[8], bv[8], acc[8];
  *(float4*)&gv[0] = *(const float4*)(gam + lane * 8);
  *(float4*)&gv[4] = *(const float4*)(gam + lane * 8 + 4);
  *(float4*)&bv[0] = *(const float4*)(bet + lane * 8);
  *(float4*)&bv[4] = *(const float4*)(bet + lane * 8 + 4);
  *(float4*)&acc[0] = *(const float4*)(dbias + lane * 8);
  *(float4*)&acc[4] = *(const float4*)(dbias + lane * 8 + 4);
#pragma unroll
  for (int t = 0; t < 7; t++) {
    float mt = __shfl(m_, t), it = __shfl(i_, t);
    int ll = l + t - 3;
    if (ll >= 0 && ll < L_SEQ) {
      bf16x8 hv = *(const bf16x8*)(in + (size_t)(row + t - 3) * CCH + lane * 8);
      float wv[8];
      *(float4*)&wv[0] = *(const float4*)(wtt + t * CCH + lane * 8);
      *(float4*)&wv[4] = *(const float4*)(wtt + t * CCH + lane * 8 + 4);
#pragma unroll
      for (int j = 0; j < 8; j++)
        acc[j] += (((float)hv[j] - mt) * it * gv[j] + bv[j]) * wv[j];
    }
  }
  bf16x8 o;
#pragma unroll
  for (int j = 0; j < 8; j++) o[j] = (bf16_t)acc[j];
  *(bf16x8*)&out[(size_t)row * CCH + lane * 8] = o;
}

// ======== GEMM core: BM=64 BN=128 BK=64, dbuf ========
#define GSTAGE64(SRCA, SRCB, BI, K0)                                              \
  do {                                                                            \
    _Pragma("unroll") for (int cc = 0; cc < 2; cc++) {                            \
      int row_ = cc * 32 + w * 8 + srow;                                          \
      int off_ = (scb ^ ((row_ & 7) << 4)) >> 1;                                  \
      gload_lds16(SRCA + (size_t)(m0 + row_) * CCH + (K0) + off_,                 \
                  &As[BI][(cc * 32 + w * 8) * 64]);                               \
    }                                                                             \
    _Pragma("unroll") for (int cc = 0; cc < 4; cc++) {                            \
      int row_ = cc * 32 + w * 8 + srow;                                          \
      int off_ = (scb ^ ((row_ & 7) << 4)) >> 1;                                  \
      gload_lds16(SRCB + (size_t)(n0 + row_) * CCH + (K0) + off_,                 \
                  &Bs[BI][(cc * 32 + w * 8) * 64]);                               \
    }                                                                             \
  } while (0)

#define GCOMP64(BI)                                                               \
  do {                                                                            \
    __builtin_amdgcn_s_setprio(1);                                                \
    _Pragma("unroll") for (int ks = 0; ks < 2; ks++) {                            \
      bf16x8 fa[2], fb[4];                                                        \
      _Pragma("unroll") for (int i = 0; i < 2; i++) {                             \
        int ra = wr * 32 + i * 16 + lc;                                           \
        fa[i] = *(const bf16x8*)&As[BI][ra * 64 +                                 \
                 (((ks * 64 + lg * 16) ^ ((ra & 7) << 4)) >> 1)];                 \
      }                                                                           \
      _Pragma("unroll") for (int j = 0; j < 4; j++) {                             \
        int rb = wc * 64 + j * 16 + lc;                                           \
        fb[j] = *(const bf16x8*)&Bs[BI][rb * 64 +                                 \
                 (((ks * 64 + lg * 16) ^ ((rb & 7) << 4)) >> 1)];                 \
      }                                                                           \
      _Pragma("unroll") for (int i = 0; i < 2; i++)                               \
        _Pragma("unroll") for (int j = 0; j < 4; j++)                             \
          acc[i][j] = __builtin_amdgcn_mfma_f32_16x16x32_bf16(fa[i], fb[j],       \
                                                              acc[i][j], 0, 0, 0);\
    }                                                                             \
    __builtin_amdgcn_s_setprio(0);                                                \
  } while (0)

// out[m,n] = A[m,:].W[n,:] (+bias, relu, +bf16 res); bf16 or fp32 out; LN partials.
template <int RELU, int RES, int OUTF32, int STATS>
__global__ __launch_bounds__(256) void gemm_kernel(const bf16_t* __restrict__ A,
                                                   const bf16_t* __restrict__ W,
                                                   const float* __restrict__ bias,
                                                   const bf16_t* __restrict__ res,
                                                   float* __restrict__ outf,
                                                   bf16_t* __restrict__ outb,
                                                   float* __restrict__ Psum,
                                                   float* __restrict__ Psq) {
  __shared__ __align__(16) bf16_t As[2][64 * 64];
  __shared__ __align__(16) bf16_t Bs[2][128 * 64];
  int tid = threadIdx.x;
  int w = tid >> 6, l = tid & 63;
  int m0 = blockIdx.x * 64, n0 = blockIdx.y * 128;
  int wr = w >> 1, wc = w & 1;
  int lc = l & 15, lg = l >> 4;
  int srow = l >> 3, scb = (l & 7) * 16;
  f32x4 acc[2][4];
#pragma unroll
  for (int i = 0; i < 2; i++)
#pragma unroll
    for (int j = 0; j < 4; j++) acc[i][j] = f32x4{0.f, 0.f, 0.f, 0.f};

  GSTAGE64(A, W, 0, 0);
  __syncthreads();
  int cur = 0;
  for (int t = 0; t < 8; t++) {
    if (t < 7) GSTAGE64(A, W, cur ^ 1, (t + 1) * 64);
    GCOMP64(cur);
    __syncthreads();
    cur ^= 1;
  }

#pragma unroll
  for (int i = 0; i < 2; i++) {
    int mbase = m0 + wr * 32 + i * 16 + lg * 4;
    float ps[2][4], pq[2][4];
    if (STATS) {
#pragma unroll
      for (int jh = 0; jh < 2; jh++)
#pragma unroll
        for (int r = 0; r < 4; r++) { ps[jh][r] = 0.f; pq[jh][r] = 0.f; }
    }
#pragma unroll
    for (int j = 0; j < 4; j++) {
      int n = n0 + wc * 64 + j * 16 + lc;
      float bn = bias[n];
#pragma unroll
      for (int r = 0; r < 4; r++) {
        int m = mbase + r;
        float v2 = acc[i][j][r] + bn;
        if (RELU) v2 = fmaxf(v2, 0.f);
        if (RES) v2 += (float)res[(size_t)m * CCH + n];
        if (OUTF32) outf[(size_t)m * CCH + n] = v2;
        else outb[(size_t)m * CCH + n] = (bf16_t)v2;
        if (STATS) { ps[j >> 1][r] += v2; pq[j >> 1][r] += v2 * v2; }
      }
    }
    if (STATS) {
#pragma unroll
      for (int jh = 0; jh < 2; jh++)
#pragma unroll
        for (int r = 0; r < 4; r++) {
          float s = ps[jh][r], q = pq[jh][r];
          s += __shfl_xor(s, 1); q += __shfl_xor(q, 1);
          s += __shfl_xor(s, 2); q += __shfl_xor(q, 2);
          s += __shfl_xor(s, 4); q += __shfl_xor(q, 4);
          s += __shfl_xor(s, 8); q += __shfl_xor(q, 8);
          if (lc == 0) {
            size_t row = mbase + r;
            Psum[row * 16 + blockIdx.y * 4 + wc * 2 + jh] = s;
            Psq[row * 16 + blockIdx.y * 4 + wc * 2 + jh] = q;
          }
        }
    }
  }
}

// ======== qkv core: BM=32 BN=256 BK=64 ========
#define GEMM_STAGE(SRCA, SRCB, BI, K0)                                            \
  do {                                                                            \
    {                                                                             \
      int row_ = w * 8 + srow;                                                    \
      int off_ = (scb ^ ((row_ & 7) << 4)) >> 1;                                  \
      gload_lds16(SRCA + (size_t)(m0 + row_) * CCH + (K0) + off_,                 \
                  &As[BI][(w * 8) * 64]);                                         \
    }                                                                             \
    _Pragma("unroll") for (int cc = 0; cc < 8; cc++) {                            \
      int row_ = cc * 32 + w * 8 + srow;                                          \
      int off_ = (scb ^ ((row_ & 7) << 4)) >> 1;                                  \
      gload_lds16(SRCB + (size_t)(n0 + row_) * CCH + (K0) + off_,                 \
                  &Bs[BI][(cc * 32 + w * 8) * 64]);                               \
    }                                                                             \
  } while (0)

#define GEMM_COMPUTE(BI)                                                          \
  do {                                                                            \
    __builtin_amdgcn_s_setprio(1);                                                \
    _Pragma("unroll") for (int ks = 0; ks < 2; ks++) {                            \
      bf16x8 fa[2], fb[4];                                                        \
      _Pragma("unroll") for (int i = 0; i < 2; i++) {                             \
        int ra = i * 16 + lc;                                                     \
        fa[i] = *(const bf16x8*)&As[BI][ra * 64 +                                 \
                 (((ks * 64 + lg * 16) ^ ((ra & 7) << 4)) >> 1)];                 \
      }                                                                           \
      _Pragma("unroll") for (int j = 0; j < 4; j++) {                             \
        int rb = w * 64 + j * 16 + lc;                                            \
        fb[j] = *(const bf16x8*)&Bs[BI][rb * 64 +                                 \
                 (((ks * 64 + lg * 16) ^ ((rb & 7) << 4)) >> 1)];                 \
      }                                                                           \
      _Pragma("unroll") for (int i = 0; i < 2; i++)                               \
        _Pragma("unroll") for (int j = 0; j < 4; j++)                             \
          acc[i][j] = __builtin_amdgcn_mfma_f32_16x16x32_bf16(fa[i], fb[j],       \
                                                              acc[i][j], 0, 0, 0);\
    }                                                                             \
    __builtin_amdgcn_s_setprio(0);                                                \
  } while (0)

__global__ __launch_bounds__(256) void qkv_kernel(const bf16_t* __restrict__ A,
                                                  const bf16_t* __restrict__ Wqkv,
                                                  const float* __restrict__ bq,
                                                  const float* __restrict__ bk,
                                                  const float* __restrict__ bv,
                                                  bf16_t* __restrict__ QB,
                                                  bf16_t* __restrict__ KB,
                                                  bf16_t* __restrict__ VT) {
  __shared__ __align__(16) bf16_t As[2][32 * 64];
  __shared__ __align__(16) bf16_t Bs[2][256 * 64];
  int tid = threadIdx.x;
  int w = tid >> 6, l = tid & 63;
  int m0 = blockIdx.x * 32, n0 = blockIdx.y * 256;
  int sec = n0 >> 9;
  int lc = l & 15, lg = l >> 4;
  int srow = l >> 3, scb = (l & 7) * 16;
  f32x4 acc[2][4];
#pragma unroll
  for (int i = 0; i < 2; i++)
#pragma unroll
    for (int j = 0; j < 4; j++) acc[i][j] = f32x4{0.f, 0.f, 0.f, 0.f};

  GEMM_STAGE(A, Wqkv, 0, 0);
  __syncthreads();
  int cur = 0;
  for (int t = 0; t < 8; t++) {
    if (t < 7) GEMM_STAGE(A, Wqkv, cur ^ 1, (t + 1) * 64);
    GEMM_COMPUTE(cur);
    __syncthreads();
    cur ^= 1;
  }

  const float* bp = (sec == 0) ? bq : (sec == 1) ? bk : bv;
#pragma unroll
  for (int i = 0; i < 2; i++) {
    int mbase = m0 + i * 16 + lg * 4;
#pragma unroll
    for (int j = 0; j < 4; j++) {
      int n = n0 + w * 64 + j * 16 + lc;
      int nl = n & 511;
      float bn = bp[nl];
      if (sec < 2) {
        bf16_t* ob = (sec == 0) ? QB : KB;
#pragma unroll
        for (int r = 0; r < 4; r++)
          ob[(size_t)(mbase + r) * CCH + nl] = (bf16_t)(acc[i][j][r] + bn);
      } else {
        int h = nl >> 6, d = nl & 63;
        int b = mbase >> 10, lpos = mbase & 1023;
        bf16x4 t;
#pragma unroll
        for (int r = 0; r < 4; r++) t[r] = (bf16_t)(acc[i][j][r] + bn);
        *(bf16x4*)&VT[(((size_t)(b * 8 + h) * 64 + d) * L_SEQ) + lpos] = t;
      }
    }
  }
}

// ---------------- flash attention (QBLK=128, dbuf K/V, setprio) ----------------
#define ATT_STAGE(BI, KC)                                                         \
  do {                                                                            \
    _Pragma("unroll") for (int r = 0; r < 2; r++) {                               \
      int row = r * 32 + w * 8 + srow;                                            \
      int sc = (scb ^ ((row & 7) << 4)) >> 1;                                     \
      int key = (KC) * 64 + row;                                                  \
      gload_lds16(K + ((size_t)(b * L_SEQ + key) * CCH + h * 64 + sc),            \
                  &Ks[BI][(r * 32 + w * 8) * 64]);                                \
      gload_lds16(VT + (((size_t)(b * 8 + h) * 64 + row) * L_SEQ + (KC) * 64 + sc),\
                  &Vs[BI][(r * 32 + w * 8) * 64]);                                \
    }                                                                             \
  } while (0)

__global__ __launch_bounds__(256) void attn_kernel(const bf16_t* __restrict__ Q,
                                                   const bf16_t* __restrict__ K,
                                                   const bf16_t* __restrict__ VT,
                                                   const float* __restrict__ mask,
                                                   bf16_t* __restrict__ O) {
  __shared__ __align__(16) bf16_t Ks[2][64 * 64];
  __shared__ __align__(16) bf16_t Vs[2][64 * 64];
  __shared__ __align__(16) bf16_t Pl[4][16 * 64];
  int tid = threadIdx.x;
  int w = tid >> 6, l = tid & 63;
  int bid = blockIdx.x;
  int sw = (bid & 7) * 64 + (bid >> 3);
  int qb = sw & 7, h = (sw >> 3) & 7, b = sw >> 6;
  int lg = l >> 4, lc = l & 15;

  bf16x8 qf[2][2];
#pragma unroll
  for (int s = 0; s < 2; s++) {
    int qrow = qb * 128 + s * 64 + w * 16 + lc;
    const bf16_t* qptr = Q + ((size_t)(b * L_SEQ + qrow) * CCH + h * 64);
    qf[s][0] = *(const bf16x8*)(qptr + lg * 8);
    qf[s][1] = *(const bf16x8*)(qptr + 32 + lg * 8);
  }

  f32x4 oacc[2][4];
  float psl[2][4];
#pragma unroll
  for (int s = 0; s < 2; s++)
#pragma unroll
    for (int nf = 0; nf < 4; nf++) {
      oacc[s][nf] = f32x4{0.f, 0.f, 0.f, 0.f};
      psl[s][nf] = 0.f;
    }

  int srow = l >> 3;
  int scb = (l & 7) * 16;

  ATT_STAGE(0, 0);
  __syncthreads();
  int cur = 0;
  for (int kc = 0; kc < 16; kc++) {
    if (kc < 15) ATT_STAGE(cur ^ 1, kc + 1);

    float mv[4];
#pragma unroll
    for (int kf = 0; kf < 4; kf++) mv[kf] = mask[b * L_SEQ + kc * 64 + kf * 16 + lc];

#pragma unroll
    for (int s = 0; s < 2; s++) {
      f32x4 sacc[4];
#pragma unroll
      for (int kf = 0; kf < 4; kf++) sacc[kf] = f32x4{0.f, 0.f, 0.f, 0.f};
      __builtin_amdgcn_s_setprio(1);
#pragma unroll
      for (int kf = 0; kf < 4; kf++) {
        int row = kf * 16 + lc;
        int sx = (row & 7) << 4;
        const bf16_t* kr = &Ks[cur][row * 64];
        bf16x8 b0 = *(const bf16x8*)(kr + (((lg * 16) ^ sx) >> 1));
        sacc[kf] = __builtin_amdgcn_mfma_f32_16x16x32_bf16(qf[s][0], b0, sacc[kf], 0, 0, 0);
        bf16x8 b1 = *(const bf16x8*)(kr + (((64 + lg * 16) ^ sx) >> 1));
        sacc[kf] = __builtin_amdgcn_mfma_f32_16x16x32_bf16(qf[s][1], b1, sacc[kf], 0, 0, 0);
      }
      __builtin_amdgcn_s_setprio(0);

#pragma unroll
      for (int kf = 0; kf < 4; kf++) {
        float mneg = (1.f - mv[kf]) * (-1e30f);
        float msc = 0.125f * mv[kf];
#pragma unroll
        for (int j = 0; j < 4; j++) {
          float p = __expf(sacc[kf][j] * msc + mneg);
          psl[s][j] += p;
          int q = lg * 4 + j;
          int cb = (kf * 32 + lc * 2) ^ ((q & 7) << 4);
          Pl[w][(q * 128 + cb) >> 1] = (bf16_t)p;
        }
      }

      int sp = (lc & 7) << 4;
      bf16x8 pa0 = *(const bf16x8*)&Pl[w][(lc * 128 + ((lg * 16) ^ sp)) >> 1];
      bf16x8 pa1 = *(const bf16x8*)&Pl[w][(lc * 128 + ((64 + lg * 16) ^ sp)) >> 1];
      __builtin_amdgcn_s_setprio(1);
#pragma unroll
      for (int nf = 0; nf < 4; nf++) {
        int d = nf * 16 + lc;
        int sx = (d & 7) << 4;
        const bf16_t* vr = &Vs[cur][d * 64];
        bf16x8 vb0 = *(const bf16x8*)(vr + (((lg * 16) ^ sx) >> 1));
        oacc[s][nf] = __builtin_amdgcn_mfma_f32_16x16x32_bf16(pa0, vb0, oacc[s][nf], 0, 0, 0);
        bf16x8 vb1 = *(const bf16x8*)(vr + (((64 + lg * 16) ^ sx) >> 1));
        oacc[s][nf] = __builtin_amdgcn_mfma_f32_16x16x32_bf16(pa1, vb1, oacc[s][nf], 0, 0, 0);
      }
      __builtin_amdgcn_s_setprio(0);
    }
    __syncthreads();
    cur ^= 1;
  }

#pragma unroll
  for (int off = 1; off < 16; off <<= 1)
#pragma unroll
    for (int s = 0; s < 2; s++)
#pragma unroll
      for (int j = 0; j < 4; j++) psl[s][j] += __shfl_xor(psl[s][j], off);

#pragma unroll
  for (int s = 0; s < 2; s++)
#pragma unroll
    for (int j = 0; j < 4; j++) {
      float is = 1.0f / psl[s][j];
      int r = qb * 128 + s * 64 + w * 16 + lg * 4 + j;
      bf16_t* op = O + ((size_t)(b * L_SEQ + r) * CCH + h * 64);
#pragma unroll
      for (int nf = 0; nf < 4; nf++) op[nf * 16 + lc] = (bf16_t)(oacc[s][nf][j] * is);
    }
}

// ---------------- launcher ----------------
extern "C" void kernel_launch(void* const* d_in, const int* in_sizes, int n_in,
                              void* d_out, int out_size, void* d_ws, size_t ws_size,
                              hipStream_t stream) {
  const float* x = (const float*)d_in[0];
  const float* mask = (const float*)d_in[1];
  const float* dw_w = (const float*)d_in[2];
  const float* dw_b = (const float*)d_in[3];
  const float* pw_w = (const float*)d_in[4];
  const float* pw_b = (const float*)d_in[5];
  const float* ln_conv_g = (const float*)d_in[6];
  const float* ln_conv_b = (const float*)d_in[7];
  const float* Wq = (const float*)d_in[8];  const float* bq = (const float*)d_in[9];
  const float* Wk = (const float*)d_in[10]; const float* bk = (const float*)d_in[11];
  const float* Wv = (const float*)d_in[12]; const float* bv = (const float*)d_in[13];
  const float* Wo = (const float*)d_in[14]; const float* bo = (const float*)d_in[15];
  const float* ln_att_g = (const float*)d_in[16]; const float* ln_att_b = (const float*)d_in[17];
  const float* Wf = (const float*)d_in[18]; const float* bfc = (const float*)d_in[19];
  const float* ln_fc_g = (const float*)d_in[20]; const float* ln_fc_b = (const float*)d_in[21];

  char* ws = (char*)d_ws;
  bf16_t* ABF  = (bf16_t*)(ws);                      // 8 MiB
  bf16_t* QB   = (bf16_t*)(ws + (8u << 20));         // 8 MiB
  bf16_t* KB   = (bf16_t*)(ws + (16u << 20));        // 8 MiB
  bf16_t* VT   = (bf16_t*)(ws + (24u << 20));        // 8 MiB  [b][h][d][key]
  char*   wb   = ws + (32u << 20);
  bf16_t* WPW  = (bf16_t*)(wb);                      // 2 MiB
  bf16_t* WQKV = (bf16_t*)(wb + (2u << 20));         // 1.5 MiB
  bf16_t* WOB  = (bf16_t*)(wb + 3584u * 1024);       // 0.5 MiB
  bf16_t* WFB  = (bf16_t*)(wb + (4u << 20));         // 0.5 MiB
  float*  WT   = (float*)(wb + 4608u * 1024);        // 56 KiB
  float*  Psum = (float*)(ws + (38u << 20));         // 512 KiB (16 chunks)
  float*  Psq  = (float*)(ws + (38u << 20) + 524288);// 512 KiB
  bf16_t* OUT  = (bf16_t*)(ws + (40u << 20));        // 8 MiB bf16 residual

  prep_kernel<<<15416, 256, 0, stream>>>(x, pw_w, Wq, Wk, Wv, Wo, Wf, dw_w,
                                         WPW, WQKV, WOB, WFB, WT,
                                         OUT, Psum, Psq);

  dim3 ggrid(128, 4);
  for (int i = 0; i < 4; i++) {
    dwln_kernel<<<2048, 256, 0, stream>>>(OUT, Psum, Psq, ln_conv_g + i * 512,
                                          ln_conv_b + i * 512, WT + i * 3584,
                                          dw_b + i * 512, ABF);
    gemm_kernel<1, 1, 0, 1><<<ggrid, 256, 0, stream>>>(ABF, WPW + i * 262144,
                                                       pw_b + i * 512, OUT,
                                                       nullptr, OUT, Psum, Psq);
  }
  // attention
  ln_apply_kernel<<<2048, 256, 0, stream>>>(OUT, Psum, Psq, ln_att_g, ln_att_b, ABF);
  qkv_kernel<<<dim3(256, 6), 256, 0, stream>>>(ABF, WQKV, bq, bk, bv, QB, KB, VT);
  attn_kernel<<<512, 256, 0, stream>>>(QB, KB, VT, mask, ABF);
  gemm_kernel<0, 1, 0, 1><<<ggrid, 256, 0, stream>>>(ABF, WOB, bo, OUT,
                                                     nullptr, OUT, Psum, Psq);
  // FC
  ln_apply_kernel<<<2048, 256, 0, stream>>>(OUT, Psum, Psq, ln_fc_g, ln_fc_b, ABF);
  gemm_kernel<1, 1, 1, 0><<<ggrid, 256, 0, stream>>>(ABF, WFB, bfc, OUT,
                                                     (float*)d_out, nullptr,
                                                     nullptr, nullptr);
}